// Round 11
// baseline (52.016 us; speedup 1.0000x reference)
//
#include <hip/hip_runtime.h>
#include <hip/hip_bf16.h>

typedef float f32x4  __attribute__((ext_vector_type(4)));
typedef float f32x16 __attribute__((ext_vector_type(16)));
typedef long  l2     __attribute__((ext_vector_type(2)));

// ---------------------------------------------------------------------------
// async global->LDS, 16B per lane. LDS dest is wave-uniform base (+lane*16).
// ---------------------------------------------------------------------------
__device__ __forceinline__ void gld16(const void* g, void* l) {
    __builtin_amdgcn_global_load_lds(
        (const __attribute__((address_space(1))) void*)g,
        (__attribute__((address_space(3))) void*)l,
        16, 0, 0);
}

// gelu, tanh approximation (matches jax.nn.gelu approximate=True)
__device__ __forceinline__ float gelu_tanh(float x) {
    float u = 0.7978845608028654f * x * (1.0f + 0.044715f * x * x);
    float e = __expf(2.0f * u);
    float t = 1.0f - 2.0f / (e + 1.0f);   // tanh(u)
    return 0.5f * x * (1.0f + t);
}

// ---------------------------------------------------------------------------
// Pre-permuted fp8 layout for the 32x32x16 MFMA (A[M][K] and BT[N][K]):
// within each row's 64B k-segment (4 k-steps s of 16 bytes, halves h of 8):
//   p = s>>1, odd = s&1, chunk c = 2p + h, stored chunk c' = c ^ ((row>>1)&3)
//   dest = c'*16 + odd*8 + j
// GEMM: lane (h = lane>>5) reads ds_read_b128 at row*64 + ((2p+h)^xor)*16:
//   lo 8B = k-step 2p (bytes j=0..7 of half h), hi 8B = k-step 2p+1.
// Bank spread: 4-way max per 32-lane half (free per m136 for b128).
// ---------------------------------------------------------------------------

// Fused quantize kernel: blocks [0, nA) do x -> Aq; blocks [nA, nA+nB) do
// w -> BTq (transpose via LDS). Single launch so the two halves overlap.
__global__ __launch_bounds__(256) void quant_fused_kernel(
        const float* __restrict__ x,  unsigned char* __restrict__ Aq,
        const float* __restrict__ w,  unsigned char* __restrict__ BTq,
        int nA, int K, int N) {
    __shared__ unsigned char lds[64 * 68];
    const int tid = threadIdx.x;

    if (blockIdx.x < nA) {
        // ---- quantA: 256 threads x float4
        int i = blockIdx.x * 256 + tid;
        float4 v = reinterpret_cast<const float4*>(x)[i];
        int pk = 0;
        pk = __builtin_amdgcn_cvt_pk_fp8_f32(v.x, v.y, pk, false);
        pk = __builtin_amdgcn_cvt_pk_fp8_f32(v.z, v.w, pk, true);
        const long k4 = (long)i * 4;
        const int  row = (int)(k4 / K);
        const int  k   = (int)(k4 % K);
        const int  o   = k & 63;
        const int  s   = o >> 4;
        const int  h   = (o >> 3) & 1;
        const int  c2  = (((s >> 1) << 1) | h) ^ ((row >> 1) & 3);
        *reinterpret_cast<unsigned int*>(
            Aq + (long)row * K + (k & ~63) + (c2 << 4) + ((s & 1) << 3) + (k & 7))
            = (unsigned int)pk;
        return;
    }

    // ---- quantBT: 64x64 tile transpose through LDS
    const int bid = blockIdx.x - nA;
    const int n0 = (bid & (N / 64 - 1)) * 64;
    const int k0 = (bid / (N / 64)) * 64;

    #pragma unroll
    for (int p = 0; p < 4; ++p) {
        int s = p * 256 + tid;
        int r = s >> 4;          // k within tile (0..63)
        int c = s & 15;          // float4 group (covers n = 4c..4c+3)
        float4 v = *reinterpret_cast<const float4*>(
            w + (long)(k0 + r) * N + n0 + c * 4);
        int pk = 0;
        pk = __builtin_amdgcn_cvt_pk_fp8_f32(v.x, v.y, pk, false);
        pk = __builtin_amdgcn_cvt_pk_fp8_f32(v.z, v.w, pk, true);
        *reinterpret_cast<unsigned int*>(&lds[r * 68 + c * 4]) = (unsigned int)pk;
    }
    __syncthreads();
    #pragma unroll
    for (int p = 0; p < 4; ++p) {
        int sidx = p * 256 + tid;
        int n  = sidx >> 4;      // n within tile (0..63)
        int kg = sidx & 15;      // k group of 4 (orig offset kg*4)
        unsigned int wv = 0;
        #pragma unroll
        for (int j = 0; j < 4; ++j)
            wv |= (unsigned int)lds[(kg * 4 + j) * 68 + n] << (8 * j);
        const int nn  = n0 + n;
        const int s   = kg >> 2;          // k-step
        const int h   = (kg >> 1) & 1;    // half
        const int c2  = (((s >> 1) << 1) | h) ^ ((nn >> 1) & 3);
        *reinterpret_cast<unsigned int*>(
            BTq + (long)nn * K + k0 + (c2 << 4) + ((s & 1) << 3) + ((kg & 1) * 4))
            = wv;
    }
}

// ---------------------------------------------------------------------------
// fp8 GEMM with 32x32x16 MFMA (2x FLOP per LDS byte vs 16x16x32).
// 128x256 tile, BK=64, 8 waves (2M x 4N), wave output 64x64 (2x2 of 32x32).
// 2 LDS buffers x 24 KB = 48 KB -> 2 blocks/CU. Round-10 2-phase skeleton:
// per K-tile 2 phases of 8 MFMA; stages A+B0 | B1 for t+1; boundary vmcnt(0).
// Epilogue: bias + gelu, wave-private LDS transpose [32][33], f32x4 nt stores.
// ---------------------------------------------------------------------------
__global__ __launch_bounds__(512, 4) void gemm_fp8_kernel(
        const unsigned char* __restrict__ A,   // [M][K] fp8 (permuted layout)
        const unsigned char* __restrict__ BT,  // [N][K] fp8 (permuted layout)
        const float* __restrict__ bias,        // [N]
        float* __restrict__ out,               // [M][N] f32
        int M, int N, int K) {
    constexpr int BM = 128, BN = 256, BK = 64;
    __shared__ union {
        unsigned char buf[2][(BM + BN) * BK];   // 2 x 24 KB (A 8K + B 16K)
        float ep[8][1056];                      // epilogue 32x33 f32 per wave
    } sm;

    const int tid  = threadIdx.x;
    const int lane = tid & 63;
    const int wid  = tid >> 6;            // 0..7
    const int wm   = wid >> 2;            // 0..1 (64 rows each)
    const int wn   = wid & 3;             // 0..3 (64 cols each)

    // XCD mapping: 8 XCDs over the 32x16 tile grid, each an 8x8 rectangle.
    // Bijective: 512 = 8 * 64.
    const int bid = blockIdx.x;
    const int xcd = bid & 7, idx = bid >> 3;            // idx 0..63
    const int tile_m = (xcd >> 1) * 8 + (idx & 7);      // 0..31
    const int tile_n = (xcd & 1) * 8 + (idx >> 3);      // 0..15
    const int m0 = tile_m * BM, n0 = tile_n * BN;

    const int l31 = lane & 31;
    const int h   = lane >> 5;            // k-half selector

    // staging: one gld16 per thread per 8KB half (128 rows x 64B)
    const int srow   = tid >> 2;          // 0..127
    const int schunk = (tid & 3) << 4;
    const unsigned char* gA = A  + (long)(m0 + srow) * K + schunk;
    const unsigned char* gB = BT + (long)(n0 + srow) * K + schunk;

    // fragment read offsets: A rows [0,128) at base 0; B rows [0,256) at 8192
    int offA[2][2], offB[2][2];
    #pragma unroll
    for (int f = 0; f < 2; ++f) {
        const int rA = wm * 64 + f * 32 + l31;
        const int rB = wn * 64 + f * 32 + l31;
        const int xA = (rA >> 1) & 3, xB = (rB >> 1) & 3;
        #pragma unroll
        for (int p = 0; p < 2; ++p) {
            offA[f][p] = rA * 64 + ((((p << 1) | h) ^ xA) << 4);
            offB[f][p] = 8192 + rB * 64 + ((((p << 1) | h) ^ xB) << 4);
        }
    }

    f32x16 acc00 = {}, acc01 = {}, acc10 = {}, acc11 = {};

    const int NT = K / BK;  // 16

#define STAGE_A(BB, TT)                                                   \
    gld16(gA + (long)(TT) * BK, &sm.buf[BB][wid * 1024])
#define STAGE_B(BB, H, TT)                                                \
    gld16(gB + (long)(H) * 128 * K + (long)(TT) * BK,                     \
          &sm.buf[BB][8192 + (H) * 8192 + wid * 1024])

#define MFMA8(P)                                                          \
    do {                                                                  \
        acc00 = __builtin_amdgcn_mfma_f32_32x32x16_fp8_fp8(a0[0], b0[0], acc00, 0, 0, 0); \
        acc01 = __builtin_amdgcn_mfma_f32_32x32x16_fp8_fp8(a0[0], b1[0], acc01, 0, 0, 0); \
        acc10 = __builtin_amdgcn_mfma_f32_32x32x16_fp8_fp8(a1[0], b0[0], acc10, 0, 0, 0); \
        acc11 = __builtin_amdgcn_mfma_f32_32x32x16_fp8_fp8(a1[0], b1[0], acc11, 0, 0, 0); \
        acc00 = __builtin_amdgcn_mfma_f32_32x32x16_fp8_fp8(a0[1], b0[1], acc00, 0, 0, 0); \
        acc01 = __builtin_amdgcn_mfma_f32_32x32x16_fp8_fp8(a0[1], b1[1], acc01, 0, 0, 0); \
        acc10 = __builtin_amdgcn_mfma_f32_32x32x16_fp8_fp8(a1[1], b0[1], acc10, 0, 0, 0); \
        acc11 = __builtin_amdgcn_mfma_f32_32x32x16_fp8_fp8(a1[1], b1[1], acc11, 0, 0, 0); \
    } while (0)

    // prologue: stage tile 0 into buf 0
    STAGE_A(0, 0); STAGE_B(0, 0, 0); STAGE_B(0, 1, 0);
    asm volatile("s_waitcnt vmcnt(0)" ::: "memory");
    __builtin_amdgcn_s_barrier();

    for (int t = 0; t < NT; ++t) {
        const int cur = t & 1, nxt = cur ^ 1;
        const unsigned char* sL = &sm.buf[cur][0];
        const bool st = (t + 1 < NT);
        l2 a0, a1, b0, b1;

        // ---- phase 0: stage A,B0 of t+1; read k-steps 0,1; 8 MFMA
        if (st) { STAGE_A(nxt, t + 1); STAGE_B(nxt, 0, t + 1); }
        a0 = *reinterpret_cast<const l2*>(sL + offA[0][0]);
        a1 = *reinterpret_cast<const l2*>(sL + offA[1][0]);
        b0 = *reinterpret_cast<const l2*>(sL + offB[0][0]);
        b1 = *reinterpret_cast<const l2*>(sL + offB[1][0]);
        __builtin_amdgcn_s_barrier();
        asm volatile("s_waitcnt lgkmcnt(0)" ::: "memory");
        __builtin_amdgcn_sched_barrier(0);
        __builtin_amdgcn_s_setprio(1);
        MFMA8(0);
        __builtin_amdgcn_s_setprio(0);

        // ---- phase 1: stage B1 of t+1; read k-steps 2,3; 8 MFMA
        if (st) { STAGE_B(nxt, 1, t + 1); }
        a0 = *reinterpret_cast<const l2*>(sL + offA[0][1]);
        a1 = *reinterpret_cast<const l2*>(sL + offA[1][1]);
        b0 = *reinterpret_cast<const l2*>(sL + offB[0][1]);
        b1 = *reinterpret_cast<const l2*>(sL + offB[1][1]);
        __builtin_amdgcn_s_barrier();
        asm volatile("s_waitcnt lgkmcnt(0)" ::: "memory");
        __builtin_amdgcn_sched_barrier(0);
        __builtin_amdgcn_s_setprio(1);
        MFMA8(1);
        __builtin_amdgcn_s_setprio(0);
        __builtin_amdgcn_sched_barrier(0);

        // ---- tile boundary: drain this wave's stages for t+1, sync
        if (t < NT - 1) {
            asm volatile("s_waitcnt vmcnt(0)" ::: "memory");
            __builtin_amdgcn_sched_barrier(0);
            __builtin_amdgcn_s_barrier();
        }
    }

    // ------------------------------------------------------------------
    // epilogue: bias + gelu, wave-private LDS transpose, nt f32x4 stores.
    // 32x32 C/D layout: col = lane&31, row = (reg&3) + 8*(reg>>2) + 4*h.
    // ------------------------------------------------------------------
    __syncthreads();   // all K-loop LDS traffic complete; safe to reuse
    float* eplds = sm.ep[wid];
    const int  col0   = n0 + wn * 64;
    const long rbase0 = m0 + wm * 64;
    const float bv0 = bias[col0 + l31];
    const float bv1 = bias[col0 + 32 + l31];

#define EPI(ACC, FI, FJ, BV)                                              \
    do {                                                                  \
        _Pragma("unroll")                                                 \
        for (int r = 0; r < 16; ++r) {                                    \
            const int row = (r & 3) + 8 * (r >> 2) + 4 * h;               \
            eplds[row * 33 + l31] = gelu_tanh(ACC[r] + (BV));             \
        }                                                                 \
        asm volatile("s_waitcnt lgkmcnt(0)" ::: "memory");                \
        _Pragma("unroll")                                                 \
        for (int ps = 0; ps < 4; ++ps) {                                  \
            const int rr = ps * 8 + (lane >> 3);                          \
            f32x4 v = *reinterpret_cast<const f32x4*>(                    \
                eplds + rr * 33 + (lane & 7) * 4);                        \
            __builtin_nontemporal_store(v, reinterpret_cast<f32x4*>(      \
                out + (rbase0 + (FI) * 32 + rr) * N + col0 + (FJ) * 32    \
                    + (lane & 7) * 4));                                   \
        }                                                                 \
        asm volatile("s_waitcnt lgkmcnt(0)" ::: "memory");                \
    } while (0)

    EPI(acc00, 0, 0, bv0);
    EPI(acc01, 0, 1, bv1);
    EPI(acc10, 1, 0, bv0);
    EPI(acc11, 1, 1, bv1);
#undef STAGE_A
#undef STAGE_B
#undef MFMA8
#undef EPI
}

// ---------------------------------------------------------------------------
extern "C" void kernel_launch(void* const* d_in, const int* in_sizes, int n_in,
                              void* d_out, int out_size, void* d_ws, size_t ws_size,
                              hipStream_t stream) {
    const float* x    = (const float*)d_in[0];   // [tokens][d_in]
    const float* w    = (const float*)d_in[1];   // [d_in][units]
    const float* bias = (const float*)d_in[2];   // [units]
    float* out = (float*)d_out;

    const int units  = in_sizes[2];              // 4096
    const int dmodel = in_sizes[1] / units;      // 1024
    const int tokens = in_sizes[0] / dmodel;     // 4096

    unsigned char* Aq  = (unsigned char*)d_ws;                 // [tokens][dmodel] fp8
    unsigned char* BTq = Aq + (size_t)tokens * dmodel;         // [units][dmodel] fp8

    const int nA = tokens * dmodel / 4 / 256;                  // 4096 blocks
    const int nB = (units / 64) * (dmodel / 64);               // 1024 blocks
    quant_fused_kernel<<<dim3(nA + nB), dim3(256), 0, stream>>>(
        x, Aq, w, BTq, nA, dmodel, units);

    const int nblocks = (tokens / 128) * (units / 256);
    gemm_fp8_kernel<<<dim3(nblocks), dim3(512), 0, stream>>>(
        Aq, BTq, bias, out, tokens, units, dmodel);
}